// Round 1
// baseline (230.602 us; speedup 1.0000x reference)
//
#include <hip/hip_runtime.h>
#include <hip/hip_bf16.h>
#include <stdint.h>

// Problem constants (all static per reference)
#define TOK   16384
#define DIMM  512
#define NHEAD 16
#define HDIM  32
#define HID   2048
#define NWIN  256
#define WLEN  64
#define EPSV  1e-5f
#define SCL   0.17677669529663687f   // 32^-0.5

typedef __hip_bfloat16 bf16;
typedef __attribute__((ext_vector_type(8))) __bf16 bf16x8;
typedef __attribute__((ext_vector_type(4))) float f32x4;

// window-order row r (win*64 + l, shifted coords) -> original token row
__device__ __forceinline__ int remap_row(int r){
  int win = r >> 6, l = r & 63;
  int gh = ((win >> 4) << 3) + (l >> 3);
  int gw = ((win & 15) << 3) + (l & 7);
  int oh = (gh + 4) & 127, ow = (gw + 4) & 127;
  return (oh << 7) + ow;
}

// Swin shift-mask region id (slices: [0,120) [120,124) [124,128) on each axis)
__device__ __forceinline__ int region_of(int win, int l){
  int gh = ((win >> 4) << 3) + (l >> 3);
  int gw = ((win & 15) << 3) + (l & 7);
  int rh = (gh < 120) ? 0 : ((gh < 124) ? 1 : 2);
  int rw = (gw < 120) ? 0 : ((gw < 124) ? 1 : 2);
  return rh * 3 + rw;
}

__device__ __forceinline__ void gl_lds16(const bf16* g, bf16* l){
  __builtin_amdgcn_global_load_lds((const __attribute__((address_space(1))) void*)g,
                                   (__attribute__((address_space(3))) void*)l, 16, 0, 0);
}

// ---------------- weight fp32 -> bf16 convert (4 ranges, contiguous dst) -------------
__global__ __launch_bounds__(256) void convert_w(const float* __restrict__ a,  // qkv_w 786432
                                                 const float* __restrict__ b,  // proj_w 262144
                                                 const float* __restrict__ c,  // mlp_w1 1048576
                                                 const float* __restrict__ d,  // mlp_w2 1048576
                                                 bf16* __restrict__ dst){
  int e = (blockIdx.x * 256 + threadIdx.x) * 4;
  float4 v;
  if (e < 786432)        v = *(const float4*)(a + e);
  else if (e < 1048576)  v = *(const float4*)(b + (e - 786432));
  else if (e < 2097152)  v = *(const float4*)(c + (e - 1048576));
  else                   v = *(const float4*)(d + (e - 2097152));
  union { bf16 h[4]; int2 q; } u;
  u.h[0] = __float2bfloat16(v.x); u.h[1] = __float2bfloat16(v.y);
  u.h[2] = __float2bfloat16(v.z); u.h[3] = __float2bfloat16(v.w);
  *(int2*)(dst + e) = u.q;
}

// ---------------- LayerNorm (one wave per row), optional shift+window remap ----------
template<bool REMAP>
__global__ __launch_bounds__(256) void ln_kernel(const float* __restrict__ in,
    const float* __restrict__ w, const float* __restrict__ b, bf16* __restrict__ outp)
{
  const int wave = threadIdx.x >> 6, lane = threadIdx.x & 63;
  const int r = blockIdx.x * 4 + wave;
  const int src = REMAP ? remap_row(r) : r;
  const float4* row = (const float4*)(in + (size_t)src * DIMM);
  float4 v0 = row[lane*2], v1 = row[lane*2 + 1];
  float sm = v0.x+v0.y+v0.z+v0.w + v1.x+v1.y+v1.z+v1.w;
  float sq = v0.x*v0.x+v0.y*v0.y+v0.z*v0.z+v0.w*v0.w
           + v1.x*v1.x+v1.y*v1.y+v1.z*v1.z+v1.w*v1.w;
  #pragma unroll
  for (int off = 1; off < 64; off <<= 1){
    sm += __shfl_xor(sm, off);
    sq += __shfl_xor(sq, off);
  }
  const float mean = sm * (1.f/512.f);
  const float rstd = rsqrtf(sq*(1.f/512.f) - mean*mean + EPSV);
  const float4* wp = (const float4*)w; const float4* bp = (const float4*)b;
  float4 w0 = wp[lane*2], w1 = wp[lane*2+1], b0 = bp[lane*2], b1 = bp[lane*2+1];
  union { bf16 h[8]; int4 q; } u;
  u.h[0] = __float2bfloat16((v0.x-mean)*rstd*w0.x + b0.x);
  u.h[1] = __float2bfloat16((v0.y-mean)*rstd*w0.y + b0.y);
  u.h[2] = __float2bfloat16((v0.z-mean)*rstd*w0.z + b0.z);
  u.h[3] = __float2bfloat16((v0.w-mean)*rstd*w0.w + b0.w);
  u.h[4] = __float2bfloat16((v1.x-mean)*rstd*w1.x + b1.x);
  u.h[5] = __float2bfloat16((v1.y-mean)*rstd*w1.y + b1.y);
  u.h[6] = __float2bfloat16((v1.z-mean)*rstd*w1.z + b1.z);
  u.h[7] = __float2bfloat16((v1.w-mean)*rstd*w1.w + b1.w);
  *(int4*)(outp + (size_t)r*DIMM + lane*8) = u.q;
}

// ---------------- GEMM: out[m,n] = sum_k A[m,k]*W[n,k]  (both K-contiguous bf16) -----
// m97 structure: 128x128 tile, BK=32, 4 waves x (4x4) 16x16x32 bf16 MFMA frags,
// global_load_lds width-16 staging, 2 barriers / K-step.
#define M_QKV  0
#define M_PROJ 1
#define M_MLP1 2
#define M_MLP2 3

template<int MODE, int K>
__global__ __launch_bounds__(256) void gemm_bt(const bf16* __restrict__ A,
    const bf16* __restrict__ Wt, const float* __restrict__ bias,
    bf16* __restrict__ out_b, float* __restrict__ out_f, const float* __restrict__ skip)
{
  __shared__ bf16 lsA[128*32];
  __shared__ bf16 lsB[128*32];
  const int tid = threadIdx.x, wave = tid >> 6, lane = tid & 63;
  const int lrow = lane & 15, lgrp = lane >> 4;
  const int m0 = blockIdx.x * 128, n0 = blockIdx.y * 128;
  const int wr = (wave >> 1) * 64, wc = (wave & 1) * 64;

  f32x4 acc[4][4] = {};

  const bf16* Abase = A  + (size_t)m0 * K;
  const bf16* Bbase = Wt + (size_t)n0 * K;
  const int srow = tid >> 2;          // 0..63
  const int scol = (tid & 3) * 8;     // 0,8,16,24

  #define STAGE(kt) { \
    gl_lds16(Abase + (size_t)(srow)      * K + (kt) + scol, lsA + wave*512); \
    gl_lds16(Abase + (size_t)(srow + 64) * K + (kt) + scol, lsA + 2048 + wave*512); \
    gl_lds16(Bbase + (size_t)(srow)      * K + (kt) + scol, lsB + wave*512); \
    gl_lds16(Bbase + (size_t)(srow + 64) * K + (kt) + scol, lsB + 2048 + wave*512); \
  }

  STAGE(0);
  __syncthreads();
  for (int kt = 0; kt < K; kt += 32){
    bf16x8 af[4], bfv[4];
    #pragma unroll
    for (int i = 0; i < 4; i++){
      af[i]  = *(const bf16x8*)(lsA + (wr + i*16 + lrow)*32 + lgrp*8);
      bfv[i] = *(const bf16x8*)(lsB + (wc + i*16 + lrow)*32 + lgrp*8);
    }
    #pragma unroll
    for (int i = 0; i < 4; i++)
      #pragma unroll
      for (int j = 0; j < 4; j++)
        acc[i][j] = __builtin_amdgcn_mfma_f32_16x16x32_bf16(af[i], bfv[j], acc[i][j], 0, 0, 0);
    __syncthreads();
    if (kt + 32 < K){
      STAGE(kt + 32);
      __syncthreads();
    }
  }
  #undef STAGE

  // Epilogue. C/D frag layout: col = lane&15, row = (lane>>4)*4 + reg  [m89/m91]
  #pragma unroll
  for (int i = 0; i < 4; i++){
    #pragma unroll
    for (int j = 0; j < 4; j++){
      const int col   = n0 + wc + j*16 + lrow;
      const int row_b = m0 + wr + i*16 + lgrp*4;
      const float bv = bias[col];
      #pragma unroll
      for (int rr = 0; rr < 4; rr++){
        const int row = row_b + rr;
        float v = acc[i][j][rr] + bv;
        if constexpr (MODE == M_QKV){
          const int t = col >> 9, rem = col & 511;
          const int head = rem >> 5, hd = rem & 31;
          const int win = row >> 6, l = row & 63;
          out_b[(size_t)t * (TOK*DIMM) + ((size_t)(win*NHEAD + head)*WLEN + l)*HDIM + hd]
              = __float2bfloat16(v);
        } else if constexpr (MODE == M_PROJ){
          const int o = remap_row(row);
          out_f[(size_t)o*DIMM + col] = v + skip[(size_t)o*DIMM + col];
        } else if constexpr (MODE == M_MLP1){
          // jax.nn.gelu default: tanh approximation
          const float x3 = v*v*v;
          const float g = 0.5f*v*(1.f + tanhf(0.7978845608028654f*(v + 0.044715f*x3)));
          out_b[(size_t)row*HID + col] = __float2bfloat16(g);
        } else { // M_MLP2: output = 2*m
          out_f[(size_t)row*DIMM + col] = 2.f * v;
        }
      }
    }
  }
}

// ---------------- windowed attention: one wave per (window, head) --------------------
__global__ __launch_bounds__(256) void attn_kernel(const bf16* __restrict__ qkv,
    const float* __restrict__ rpb, bf16* __restrict__ outp)
{
  __shared__ bf16 Pl[4][64][72];   // per-wave softmaxed P, padded stride 72
  const int wave = threadIdx.x >> 6, lane = threadIdx.x & 63;
  const int lrow = lane & 15, lgrp = lane >> 4;
  const int wh = blockIdx.x * 4 + wave;      // 0..4095
  const int win = wh >> 4, head = wh & 15;
  const bf16* qb = qkv + (size_t)wh * (WLEN*HDIM);
  const bf16* kb = qb + (size_t)TOK * DIMM;
  const bf16* vb = kb + (size_t)TOK * DIMM;

  bf16x8 aq[4], ak[4];
  #pragma unroll
  for (int i = 0; i < 4; i++){
    aq[i] = *(const bf16x8*)(qb + (i*16 + lrow)*HDIM + lgrp*8);
    ak[i] = *(const bf16x8*)(kb + (i*16 + lrow)*HDIM + lgrp*8);
  }
  f32x4 s[4][4] = {};
  #pragma unroll
  for (int i = 0; i < 4; i++)
    #pragma unroll
    for (int j = 0; j < 4; j++)
      s[i][j] = __builtin_amdgcn_mfma_f32_16x16x32_bf16(aq[i], ak[j], s[i][j], 0, 0, 0);

  // scale + rel-pos bias + shift mask + row softmax (rows of S span the 16-lane group)
  #pragma unroll
  for (int i = 0; i < 4; i++){
    #pragma unroll
    for (int rr = 0; rr < 4; rr++){
      const int srow = i*16 + lgrp*4 + rr;
      const int rq = region_of(win, srow);
      float vals[4]; float mx = -1e30f;
      #pragma unroll
      for (int j = 0; j < 4; j++){
        const int scol = j*16 + lrow;
        const int idx = ((srow>>3) - (scol>>3) + 7)*15 + ((srow&7) - (scol&7) + 7);
        float v = s[i][j][rr]*SCL + rpb[idx*NHEAD + head];
        if (region_of(win, scol) != rq) v -= 100.f;
        vals[j] = v; mx = fmaxf(mx, v);
      }
      mx = fmaxf(mx, __shfl_xor(mx, 1));
      mx = fmaxf(mx, __shfl_xor(mx, 2));
      mx = fmaxf(mx, __shfl_xor(mx, 4));
      mx = fmaxf(mx, __shfl_xor(mx, 8));
      float sum = 0.f;
      #pragma unroll
      for (int j = 0; j < 4; j++){ vals[j] = __expf(vals[j] - mx); sum += vals[j]; }
      sum += __shfl_xor(sum, 1); sum += __shfl_xor(sum, 2);
      sum += __shfl_xor(sum, 4); sum += __shfl_xor(sum, 8);
      const float rs = 1.f / sum;
      #pragma unroll
      for (int j = 0; j < 4; j++)
        Pl[wave][srow][j*16 + lrow] = __float2bfloat16(vals[j] * rs);
    }
  }

  // PV: O(64x32) = P(64x64) @ V(64x32), K split in 2 steps of 32
  f32x4 o[4][2] = {};
  const __bf16* vraw = (const __bf16*)vb;
  #pragma unroll
  for (int st = 0; st < 2; st++){
    bf16x8 pa[4];
    #pragma unroll
    for (int i = 0; i < 4; i++)
      pa[i] = *(const bf16x8*)(&Pl[wave][i*16 + lrow][st*32 + lgrp*8]);
    bf16x8 bv[2];
    #pragma unroll
    for (int j = 0; j < 2; j++){
      #pragma unroll
      for (int jj = 0; jj < 8; jj++)
        bv[j][jj] = vraw[(size_t)(st*32 + lgrp*8 + jj)*HDIM + j*16 + lrow];
    }
    #pragma unroll
    for (int i = 0; i < 4; i++)
      #pragma unroll
      for (int j = 0; j < 2; j++)
        o[i][j] = __builtin_amdgcn_mfma_f32_16x16x32_bf16(pa[i], bv[j], o[i][j], 0, 0, 0);
  }
  bf16* orow = outp + (size_t)win * WLEN * DIMM + head * HDIM;
  #pragma unroll
  for (int i = 0; i < 4; i++)
    #pragma unroll
    for (int j = 0; j < 2; j++)
      #pragma unroll
      for (int rr = 0; rr < 4; rr++){
        const int l = i*16 + lgrp*4 + rr;
        orow[(size_t)l * DIMM + j*16 + lrow] = __float2bfloat16(o[i][j][rr]);
      }
}

// ---------------- host launch --------------------------------------------------------
extern "C" void kernel_launch(void* const* d_in, const int* in_sizes, int n_in,
                              void* d_out, int out_size, void* d_ws, size_t ws_size,
                              hipStream_t stream) {
  const float* x     = (const float*)d_in[0];
  const float* ln1w  = (const float*)d_in[1];
  const float* ln1b  = (const float*)d_in[2];
  const float* ln2w  = (const float*)d_in[3];
  const float* ln2b  = (const float*)d_in[4];
  const float* qkvw  = (const float*)d_in[5];
  const float* qkvbi = (const float*)d_in[6];
  const float* projw = (const float*)d_in[7];
  const float* projb = (const float*)d_in[8];
  const float* rpb   = (const float*)d_in[9];
  const float* m1w   = (const float*)d_in[10];
  const float* m1b   = (const float*)d_in[11];
  const float* m2w   = (const float*)d_in[12];
  const float* m2b   = (const float*)d_in[13];

  // workspace layout (peak ~118 MiB)
  bf16* wqkv  = (bf16*)d_ws;                 // 786432
  bf16* wproj = wqkv + 786432;               // 262144
  bf16* wm1   = wproj + 262144;              // 1048576
  bf16* wm2   = wm1 + 1048576;               // 1048576
  bf16* xw    = wm2 + 1048576;               // 8388608  (LN1 out, window-ordered)
  float* hbuf = (float*)(xw + 8388608);      // 8388608 f32 (attn branch + residual)
  bf16* qkvb  = (bf16*)(hbuf + 8388608);     // 3*8388608 (q,k,v)
  bf16* attno = qkvb + 3*(size_t)8388608;    // 8388608
  bf16* m1buf = qkvb;                        // reuse qkv+attno region (33.5M elems)
  bf16* h2    = xw;                          // reuse xw (LN2 out)

  convert_w<<<3072, 256, 0, stream>>>(qkvw, projw, m1w, m2w, wqkv);
  ln_kernel<true><<<4096, 256, 0, stream>>>(x, ln1w, ln1b, xw);
  { dim3 g(TOK/128, 1536/128);
    gemm_bt<M_QKV, 512><<<g, 256, 0, stream>>>(xw, wqkv, qkvbi, qkvb, nullptr, nullptr); }
  attn_kernel<<<1024, 256, 0, stream>>>(qkvb, rpb, attno);
  { dim3 g(TOK/128, 512/128);
    gemm_bt<M_PROJ, 512><<<g, 256, 0, stream>>>(attno, wproj, projb, nullptr, hbuf, x); }
  ln_kernel<false><<<4096, 256, 0, stream>>>(hbuf, ln2w, ln2b, h2);
  { dim3 g(TOK/128, 2048/128);
    gemm_bt<M_MLP1, 512><<<g, 256, 0, stream>>>(h2, wm1, m1b, m1buf, nullptr, nullptr); }
  { dim3 g(TOK/128, 512/128);
    gemm_bt<M_MLP2, 2048><<<g, 256, 0, stream>>>(m1buf, wm2, m2b, nullptr, (float*)d_out, nullptr); }
}

// Round 2
// 227.630 us; speedup vs baseline: 1.0131x; 1.0131x over previous
//
#include <hip/hip_runtime.h>
#include <hip/hip_bf16.h>
#include <stdint.h>

// Problem constants (all static per reference)
#define TOK   16384
#define DIMM  512
#define NHEAD 16
#define HDIM  32
#define HID   2048
#define NWIN  256
#define WLEN  64
#define EPSV  1e-5f
#define SCL   0.17677669529663687f   // 32^-0.5

typedef __hip_bfloat16 bf16;
typedef __attribute__((ext_vector_type(8))) __bf16 bf16x8;
typedef __attribute__((ext_vector_type(4))) float f32x4;

// window-order row r (win*64 + l, shifted coords) -> original token row
__device__ __forceinline__ int remap_row(int r){
  int win = r >> 6, l = r & 63;
  int gh = ((win >> 4) << 3) + (l >> 3);
  int gw = ((win & 15) << 3) + (l & 7);
  int oh = (gh + 4) & 127, ow = (gw + 4) & 127;
  return (oh << 7) + ow;
}

// Swin shift-mask region id (slices: [0,120) [120,124) [124,128) on each axis)
__device__ __forceinline__ int region_of(int win, int l){
  int gh = ((win >> 4) << 3) + (l >> 3);
  int gw = ((win & 15) << 3) + (l & 7);
  int rh = (gh < 120) ? 0 : ((gh < 124) ? 1 : 2);
  int rw = (gw < 120) ? 0 : ((gw < 124) ? 1 : 2);
  return rh * 3 + rw;
}

__device__ __forceinline__ void gl_lds16(const bf16* g, bf16* l){
  __builtin_amdgcn_global_load_lds((const __attribute__((address_space(1))) void*)g,
                                   (__attribute__((address_space(3))) void*)l, 16, 0, 0);
}

// ---------------- weight fp32 -> bf16 convert (4 ranges, contiguous dst) -------------
__global__ __launch_bounds__(256) void convert_w(const float* __restrict__ a,  // qkv_w 786432
                                                 const float* __restrict__ b,  // proj_w 262144
                                                 const float* __restrict__ c,  // mlp_w1 1048576
                                                 const float* __restrict__ d,  // mlp_w2 1048576
                                                 bf16* __restrict__ dst){
  int e = (blockIdx.x * 256 + threadIdx.x) * 4;
  float4 v;
  if (e < 786432)        v = *(const float4*)(a + e);
  else if (e < 1048576)  v = *(const float4*)(b + (e - 786432));
  else if (e < 2097152)  v = *(const float4*)(c + (e - 1048576));
  else                   v = *(const float4*)(d + (e - 2097152));
  union { bf16 h[4]; int2 q; } u;
  u.h[0] = __float2bfloat16(v.x); u.h[1] = __float2bfloat16(v.y);
  u.h[2] = __float2bfloat16(v.z); u.h[3] = __float2bfloat16(v.w);
  *(int2*)(dst + e) = u.q;
}

// ---------------- LayerNorm (one wave per row), optional shift+window remap ----------
template<bool REMAP>
__global__ __launch_bounds__(256) void ln_kernel(const float* __restrict__ in,
    const float* __restrict__ w, const float* __restrict__ b, bf16* __restrict__ outp)
{
  const int wave = threadIdx.x >> 6, lane = threadIdx.x & 63;
  const int r = blockIdx.x * 4 + wave;
  const int src = REMAP ? remap_row(r) : r;
  const float4* row = (const float4*)(in + (size_t)src * DIMM);
  float4 v0 = row[lane*2], v1 = row[lane*2 + 1];
  float sm = v0.x+v0.y+v0.z+v0.w + v1.x+v1.y+v1.z+v1.w;
  float sq = v0.x*v0.x+v0.y*v0.y+v0.z*v0.z+v0.w*v0.w
           + v1.x*v1.x+v1.y*v1.y+v1.z*v1.z+v1.w*v1.w;
  #pragma unroll
  for (int off = 1; off < 64; off <<= 1){
    sm += __shfl_xor(sm, off);
    sq += __shfl_xor(sq, off);
  }
  const float mean = sm * (1.f/512.f);
  const float rstd = rsqrtf(sq*(1.f/512.f) - mean*mean + EPSV);
  const float4* wp = (const float4*)w; const float4* bp = (const float4*)b;
  float4 w0 = wp[lane*2], w1 = wp[lane*2+1], b0 = bp[lane*2], b1 = bp[lane*2+1];
  union { bf16 h[8]; int4 q; } u;
  u.h[0] = __float2bfloat16((v0.x-mean)*rstd*w0.x + b0.x);
  u.h[1] = __float2bfloat16((v0.y-mean)*rstd*w0.y + b0.y);
  u.h[2] = __float2bfloat16((v0.z-mean)*rstd*w0.z + b0.z);
  u.h[3] = __float2bfloat16((v0.w-mean)*rstd*w0.w + b0.w);
  u.h[4] = __float2bfloat16((v1.x-mean)*rstd*w1.x + b1.x);
  u.h[5] = __float2bfloat16((v1.y-mean)*rstd*w1.y + b1.y);
  u.h[6] = __float2bfloat16((v1.z-mean)*rstd*w1.z + b1.z);
  u.h[7] = __float2bfloat16((v1.w-mean)*rstd*w1.w + b1.w);
  *(int4*)(outp + (size_t)r*DIMM + lane*8) = u.q;
}

// ---------------- GEMM: out[m,n] = sum_k A[m,k]*W[n,k]  (both K-contiguous bf16) -----
// 2-phase double-buffered structure (catalog T3-lite recipe):
//   STAGE(buf0,0); barrier;
//   loop: STAGE(buf^1, next); ds_read+MFMA from buf; vmcnt(0)+barrier; swap.
// 128x128 tile, BK=32, 4 waves x (4x4) 16x16x32 bf16 MFMA frags.
// T2 swizzle / T5 setprio deliberately omitted: NULL on 2-phase (m228d/m230).
#define M_QKV  0
#define M_PROJ 1
#define M_MLP1 2
#define M_MLP2 3

template<int MODE, int K>
__global__ __launch_bounds__(256) void gemm_bt(const bf16* __restrict__ A,
    const bf16* __restrict__ Wt, const float* __restrict__ bias,
    bf16* __restrict__ out_b, float* __restrict__ out_f, const float* __restrict__ skip)
{
  __shared__ bf16 lsA[2][128*32];
  __shared__ bf16 lsB[2][128*32];
  const int tid = threadIdx.x, wave = tid >> 6, lane = tid & 63;
  const int lrow = lane & 15, lgrp = lane >> 4;
  const int m0 = blockIdx.x * 128, n0 = blockIdx.y * 128;
  const int wr = (wave >> 1) * 64, wc = (wave & 1) * 64;

  f32x4 acc[4][4] = {};

  const bf16* Abase = A  + (size_t)m0 * K;
  const bf16* Bbase = Wt + (size_t)n0 * K;
  const int srow = tid >> 2;          // 0..63
  const int scol = (tid & 3) * 8;     // 0,8,16,24

  #define STAGE(kt, bf) { \
    gl_lds16(Abase + (size_t)(srow)      * K + (kt) + scol, lsA[bf] + wave*512); \
    gl_lds16(Abase + (size_t)(srow + 64) * K + (kt) + scol, lsA[bf] + 2048 + wave*512); \
    gl_lds16(Bbase + (size_t)(srow)      * K + (kt) + scol, lsB[bf] + wave*512); \
    gl_lds16(Bbase + (size_t)(srow + 64) * K + (kt) + scol, lsB[bf] + 2048 + wave*512); \
  }

  STAGE(0, 0);
  __syncthreads();
  int cur = 0;
  for (int kt = 0; kt < K; kt += 32){
    if (kt + 32 < K) STAGE(kt + 32, cur ^ 1);   // issue next-tile loads BEFORE compute
    bf16x8 af[4], bfv[4];
    #pragma unroll
    for (int i = 0; i < 4; i++){
      af[i]  = *(const bf16x8*)(lsA[cur] + (wr + i*16 + lrow)*32 + lgrp*8);
      bfv[i] = *(const bf16x8*)(lsB[cur] + (wc + i*16 + lrow)*32 + lgrp*8);
    }
    #pragma unroll
    for (int i = 0; i < 4; i++)
      #pragma unroll
      for (int j = 0; j < 4; j++)
        acc[i][j] = __builtin_amdgcn_mfma_f32_16x16x32_bf16(af[i], bfv[j], acc[i][j], 0, 0, 0);
    __syncthreads();   // one barrier/K-step: drains vmcnt(0)+lgkmcnt(0), next buf ready
    cur ^= 1;
  }
  #undef STAGE

  // Epilogue. C/D frag layout: col = lane&15, row = (lane>>4)*4 + reg  [m89/m91]
  #pragma unroll
  for (int i = 0; i < 4; i++){
    #pragma unroll
    for (int j = 0; j < 4; j++){
      const int col   = n0 + wc + j*16 + lrow;
      const int row_b = m0 + wr + i*16 + lgrp*4;
      const float bv = bias[col];
      #pragma unroll
      for (int rr = 0; rr < 4; rr++){
        const int row = row_b + rr;
        float v = acc[i][j][rr] + bv;
        if constexpr (MODE == M_QKV){
          const int t = col >> 9, rem = col & 511;
          const int head = rem >> 5, hd = rem & 31;
          const int win = row >> 6, l = row & 63;
          out_b[(size_t)t * (TOK*DIMM) + ((size_t)(win*NHEAD + head)*WLEN + l)*HDIM + hd]
              = __float2bfloat16(v);
        } else if constexpr (MODE == M_PROJ){
          const int o = remap_row(row);
          out_f[(size_t)o*DIMM + col] = v + skip[(size_t)o*DIMM + col];
        } else if constexpr (MODE == M_MLP1){
          // tanh-GELU via sigmoid identity: 0.5*(1+tanh(u)) = sigmoid(2u)
          // g = v * sigmoid(1.59576912*(v + 0.044715 v^3)) -- one v_exp_f32
          const float u = 1.5957691216057308f * (v + 0.044715f*v*v*v);
          const float g = v * (1.0f / (1.0f + __expf(-u)));
          out_b[(size_t)row*HID + col] = __float2bfloat16(g);
        } else { // M_MLP2: output = 2*m
          out_f[(size_t)row*DIMM + col] = 2.f * v;
        }
      }
    }
  }
}

// ---------------- windowed attention: one wave per (window, head) --------------------
__global__ __launch_bounds__(256) void attn_kernel(const bf16* __restrict__ qkv,
    const float* __restrict__ rpb, bf16* __restrict__ outp)
{
  __shared__ bf16 Pl[4][64][72];   // per-wave softmaxed P, padded stride 72
  const int wave = threadIdx.x >> 6, lane = threadIdx.x & 63;
  const int lrow = lane & 15, lgrp = lane >> 4;
  const int wh = blockIdx.x * 4 + wave;      // 0..4095
  const int win = wh >> 4, head = wh & 15;
  const bf16* qb = qkv + (size_t)wh * (WLEN*HDIM);
  const bf16* kb = qb + (size_t)TOK * DIMM;
  const bf16* vb = kb + (size_t)TOK * DIMM;

  bf16x8 aq[4], ak[4];
  #pragma unroll
  for (int i = 0; i < 4; i++){
    aq[i] = *(const bf16x8*)(qb + (i*16 + lrow)*HDIM + lgrp*8);
    ak[i] = *(const bf16x8*)(kb + (i*16 + lrow)*HDIM + lgrp*8);
  }
  f32x4 s[4][4] = {};
  #pragma unroll
  for (int i = 0; i < 4; i++)
    #pragma unroll
    for (int j = 0; j < 4; j++)
      s[i][j] = __builtin_amdgcn_mfma_f32_16x16x32_bf16(aq[i], ak[j], s[i][j], 0, 0, 0);

  // scale + rel-pos bias + shift mask + row softmax (rows of S span the 16-lane group)
  #pragma unroll
  for (int i = 0; i < 4; i++){
    #pragma unroll
    for (int rr = 0; rr < 4; rr++){
      const int srow = i*16 + lgrp*4 + rr;
      const int rq = region_of(win, srow);
      float vals[4]; float mx = -1e30f;
      #pragma unroll
      for (int j = 0; j < 4; j++){
        const int scol = j*16 + lrow;
        const int idx = ((srow>>3) - (scol>>3) + 7)*15 + ((srow&7) - (scol&7) + 7);
        float v = s[i][j][rr]*SCL + rpb[idx*NHEAD + head];
        if (region_of(win, scol) != rq) v -= 100.f;
        vals[j] = v; mx = fmaxf(mx, v);
      }
      mx = fmaxf(mx, __shfl_xor(mx, 1));
      mx = fmaxf(mx, __shfl_xor(mx, 2));
      mx = fmaxf(mx, __shfl_xor(mx, 4));
      mx = fmaxf(mx, __shfl_xor(mx, 8));
      float sum = 0.f;
      #pragma unroll
      for (int j = 0; j < 4; j++){ vals[j] = __expf(vals[j] - mx); sum += vals[j]; }
      sum += __shfl_xor(sum, 1); sum += __shfl_xor(sum, 2);
      sum += __shfl_xor(sum, 4); sum += __shfl_xor(sum, 8);
      const float rs = 1.f / sum;
      #pragma unroll
      for (int j = 0; j < 4; j++)
        Pl[wave][srow][j*16 + lrow] = __float2bfloat16(vals[j] * rs);
    }
  }

  // PV: O(64x32) = P(64x64) @ V(64x32), K split in 2 steps of 32
  f32x4 o[4][2] = {};
  const __bf16* vraw = (const __bf16*)vb;
  #pragma unroll
  for (int st = 0; st < 2; st++){
    bf16x8 pa[4];
    #pragma unroll
    for (int i = 0; i < 4; i++)
      pa[i] = *(const bf16x8*)(&Pl[wave][i*16 + lrow][st*32 + lgrp*8]);
    bf16x8 bv[2];
    #pragma unroll
    for (int j = 0; j < 2; j++){
      #pragma unroll
      for (int jj = 0; jj < 8; jj++)
        bv[j][jj] = vraw[(size_t)(st*32 + lgrp*8 + jj)*HDIM + j*16 + lrow];
    }
    #pragma unroll
    for (int i = 0; i < 4; i++)
      #pragma unroll
      for (int j = 0; j < 2; j++)
        o[i][j] = __builtin_amdgcn_mfma_f32_16x16x32_bf16(pa[i], bv[j], o[i][j], 0, 0, 0);
  }
  bf16* orow = outp + (size_t)win * WLEN * DIMM + head * HDIM;
  #pragma unroll
  for (int i = 0; i < 4; i++)
    #pragma unroll
    for (int j = 0; j < 2; j++)
      #pragma unroll
      for (int rr = 0; rr < 4; rr++){
        const int l = i*16 + lgrp*4 + rr;
        orow[(size_t)l * DIMM + j*16 + lrow] = __float2bfloat16(o[i][j][rr]);
      }
}

// ---------------- host launch --------------------------------------------------------
extern "C" void kernel_launch(void* const* d_in, const int* in_sizes, int n_in,
                              void* d_out, int out_size, void* d_ws, size_t ws_size,
                              hipStream_t stream) {
  const float* x     = (const float*)d_in[0];
  const float* ln1w  = (const float*)d_in[1];
  const float* ln1b  = (const float*)d_in[2];
  const float* ln2w  = (const float*)d_in[3];
  const float* ln2b  = (const float*)d_in[4];
  const float* qkvw  = (const float*)d_in[5];
  const float* qkvbi = (const float*)d_in[6];
  const float* projw = (const float*)d_in[7];
  const float* projb = (const float*)d_in[8];
  const float* rpb   = (const float*)d_in[9];
  const float* m1w   = (const float*)d_in[10];
  const float* m1b   = (const float*)d_in[11];
  const float* m2w   = (const float*)d_in[12];
  const float* m2b   = (const float*)d_in[13];

  // workspace layout (peak ~118 MiB)
  bf16* wqkv  = (bf16*)d_ws;                 // 786432
  bf16* wproj = wqkv + 786432;               // 262144
  bf16* wm1   = wproj + 262144;              // 1048576
  bf16* wm2   = wm1 + 1048576;               // 1048576
  bf16* xw    = wm2 + 1048576;               // 8388608  (LN1 out, window-ordered)
  float* hbuf = (float*)(xw + 8388608);      // 8388608 f32 (attn branch + residual)
  bf16* qkvb  = (bf16*)(hbuf + 8388608);     // 3*8388608 (q,k,v)
  bf16* attno = qkvb + 3*(size_t)8388608;    // 8388608
  bf16* m1buf = qkvb;                        // reuse qkv+attno region (33.5M elems)
  bf16* h2    = xw;                          // reuse xw (LN2 out)

  convert_w<<<3072, 256, 0, stream>>>(qkvw, projw, m1w, m2w, wqkv);
  ln_kernel<true><<<4096, 256, 0, stream>>>(x, ln1w, ln1b, xw);
  { dim3 g(TOK/128, 1536/128);
    gemm_bt<M_QKV, 512><<<g, 256, 0, stream>>>(xw, wqkv, qkvbi, qkvb, nullptr, nullptr); }
  attn_kernel<<<1024, 256, 0, stream>>>(qkvb, rpb, attno);
  { dim3 g(TOK/128, 512/128);
    gemm_bt<M_PROJ, 512><<<g, 256, 0, stream>>>(attno, wproj, projb, nullptr, hbuf, x); }
  ln_kernel<false><<<4096, 256, 0, stream>>>(hbuf, ln2w, ln2b, h2);
  { dim3 g(TOK/128, 2048/128);
    gemm_bt<M_MLP1, 512><<<g, 256, 0, stream>>>(h2, wm1, m1b, m1buf, nullptr, nullptr); }
  { dim3 g(TOK/128, 512/128);
    gemm_bt<M_MLP2, 2048><<<g, 256, 0, stream>>>(m1buf, wm2, m2b, nullptr, (float*)d_out, nullptr); }
}